// Round 6
// baseline (237.088 us; speedup 1.0000x reference)
//
#include <hip/hip_runtime.h>
#include <hip/hip_bf16.h>
#include <cstdint>

#define N_ROWS 8192
#define DIM    1024

typedef __attribute__((ext_vector_type(4))) float  f32x4;
typedef __attribute__((ext_vector_type(8))) __bf16 bf16x8;

__device__ __forceinline__ unsigned short f2bf(float x) {
    unsigned int u = __float_as_uint(x);
    u += 0x7fffu + ((u >> 16) & 1u);   // round-to-nearest-even
    return (unsigned short)(u >> 16);
}

// ---------------------------------------------------------------------------
// Kernel 1: per-row L2 normalize (fp32 -> bf16), fp32 diagonal logit, zero S.
// PROVEN round-1..4 version: one BLOCK (256 thr) per row, 4 f32/thread.
// Also zeroes out[0] (ordered before loss_kernel's atomics by kernel boundary).
// ---------------------------------------------------------------------------
__global__ __launch_bounds__(256) void normalize_kernel(
    const float* __restrict__ A, const float* __restrict__ B,
    short* __restrict__ Abf, short* __restrict__ Bbf,
    float* __restrict__ diag, float* __restrict__ S,
    float* __restrict__ out)
{
    const int row  = blockIdx.x;
    const int t    = threadIdx.x;
    const int lane = t & 63;
    const int wave = t >> 6;

    const float4 a = reinterpret_cast<const float4*>(A)[row * (DIM / 4) + t];
    const float4 b = reinterpret_cast<const float4*>(B)[row * (DIM / 4) + t];

    float ssA = a.x * a.x + a.y * a.y + a.z * a.z + a.w * a.w;
    float ssB = b.x * b.x + b.y * b.y + b.z * b.z + b.w * b.w;
#pragma unroll
    for (int m = 1; m < 64; m <<= 1) {
        ssA += __shfl_xor(ssA, m);
        ssB += __shfl_xor(ssB, m);
    }
    __shared__ float redA[4], redB[4];
    if (lane == 0) { redA[wave] = ssA; redB[wave] = ssB; }
    __syncthreads();
    ssA = redA[0] + redA[1] + redA[2] + redA[3];
    ssB = redB[0] + redB[1] + redB[2] + redB[3];

    const float ia = 1.0f / fmaxf(sqrtf(ssA), 1e-8f);
    const float ib = 1.0f / fmaxf(sqrtf(ssB), 1e-8f);

    const float anx = a.x * ia, any = a.y * ia, anz = a.z * ia, anw = a.w * ia;
    const float bnx = b.x * ib, bny = b.y * ib, bnz = b.z * ib, bnw = b.w * ib;

    ushort4 pa, pb;
    pa.x = f2bf(anx); pa.y = f2bf(any); pa.z = f2bf(anz); pa.w = f2bf(anw);
    pb.x = f2bf(bnx); pb.y = f2bf(bny); pb.z = f2bf(bnz); pb.w = f2bf(bnw);
    reinterpret_cast<ushort4*>(Abf)[row * (DIM / 4) + t] = pa;
    reinterpret_cast<ushort4*>(Bbf)[row * (DIM / 4) + t] = pb;

    float d = anx * bnx + any * bny + anz * bnz + anw * bnw;
#pragma unroll
    for (int m = 1; m < 64; m <<= 1) d += __shfl_xor(d, m);
    __shared__ float redD[4];
    if (lane == 0) redD[wave] = d;
    __syncthreads();
    if (t == 0) {
        diag[row] = (redD[0] + redD[1] + redD[2] + redD[3]) * 10.0f;  // /T
        S[row] = 0.0f;           // ws is poisoned 0xAA each launch
        if (row == 0) out[0] = 0.0f;
    }
}

// ---------------------------------------------------------------------------
// Kernel 2: PERSISTENT 256x256x(BK=64) 8-phase bf16 GEMM (A·B^T) +
// exp(logit-10) row-sum epilogue per segment.
//   256 blocks (1/CU): tileM fixed, 4 tileN segments, flattened 64-K-tile
//   loop, continuous staging across segment boundaries.
//   Round-6: TEMPLATE-EXACT uniform staging — ONE half-tile (2 loads/thr)
//   per phase; vmcnt(6) at ph4/ph8. Ledger (steady state, iter computes
//   g,g+1):
//     entering ph1 in-flight: A1h0,B1h1,A1h1 (g+1)  [3 half-tiles]
//     ph1:+B1h0(g+1) ph2:+A0h0(g+2) ph3:+B0h1(g+2) ph4:+A0h1(g+2) -> 14 loads
//       VM6 completes the 4 oldest half-tiles = buf1(g+1) ready for ph5
//     ph5:+B0h0(g+2) ph6:+A1h0(g+3) ph7:+B1h1(g+3) ph8:+A1h1(g+3) -> 14
//       VM6 completes buf0(g+2) ready for next ph1; leaves g+3 A1/B1h1.
//   Tail g=62: ph2..ph8 stage nothing; VM0 at ph4.
//   Epilogue scratch: DEDICATED 4KB LDS at offset 131072 (no aliasing with
//   any staged region by construction). LGKM0+BAR sync only.
// ---------------------------------------------------------------------------
#define BAR()   __builtin_amdgcn_s_barrier()
#define LGKM0() asm volatile("s_waitcnt lgkmcnt(0)" ::: "memory")
#define LGKM8() asm volatile("s_waitcnt lgkmcnt(8)" ::: "memory")
#define VM6()   asm volatile("s_waitcnt vmcnt(6)" ::: "memory")
#define VM0()   asm volatile("s_waitcnt vmcnt(0)" ::: "memory")

__device__ __forceinline__ void stage_half(const short* __restrict__ gsrc,
                                           short* ldst, int t)
{
#pragma unroll
    for (int i = 0; i < 2; i++) {
        const int d    = (i * 512 + t) * 16;                 // dest byte 0..16383
        const int row  = d >> 7;                             // 0..127
        const int colb = (d & 127) ^ ((row & 7) << 4);       // swz bits4-6
        __builtin_amdgcn_global_load_lds(
            (const __attribute__((address_space(1))) void*)((const char*)gsrc + (size_t)row * (DIM * 2) + colb),
            (__attribute__((address_space(3))) void*)((char*)ldst + d), 16, 0, 0);
    }
}

template<int MH>
__device__ __forceinline__ void lda_f(const char* base, int wr, int lm, int lk,
                                      bf16x8 (&aF)[4][2])
{
#pragma unroll
    for (int m = 0; m < 4; m++)
#pragma unroll
        for (int ks = 0; ks < 2; ks++) {
            const int row = wr * 128 + MH * 64 + m * 16 + lm;
            const int b   = (row * 128 + ks * 64 + lk * 16) ^ ((row & 7) << 4);
            aF[m][ks] = *reinterpret_cast<const bf16x8*>(base + b);
        }
}

template<int NH>
__device__ __forceinline__ void ldb_f(const char* base, int wc, int lm, int lk,
                                      bf16x8 (&bF)[2][2])
{
#pragma unroll
    for (int n = 0; n < 2; n++)
#pragma unroll
        for (int ks = 0; ks < 2; ks++) {
            const int row = wc * 64 + NH * 32 + n * 16 + lm;
            const int b   = (row * 128 + ks * 64 + lk * 16) ^ ((row & 7) << 4);
            bF[n][ks] = *reinterpret_cast<const bf16x8*>(base + b);
        }
}

template<int MH, int NP>
__device__ __forceinline__ void mma16(const bf16x8 (&aF)[4][2],
                                      const bf16x8 (&bF)[2][2],
                                      f32x4 (&acc)[8][4])
{
    __builtin_amdgcn_s_setprio(1);
#pragma unroll
    for (int m = 0; m < 4; m++)
#pragma unroll
        for (int n = 0; n < 2; n++)
#pragma unroll
            for (int ks = 0; ks < 2; ks++)
                acc[MH * 4 + m][NP * 2 + n] = __builtin_amdgcn_mfma_f32_16x16x32_bf16(
                    aF[m][ks], bF[n][ks], acc[MH * 4 + m][NP * 2 + n], 0, 0, 0);
    __builtin_amdgcn_s_setprio(0);
}

__global__ __launch_bounds__(512, 2) void gemm_lse_kernel(
    const short* __restrict__ Abf, const short* __restrict__ Bbf,
    float* __restrict__ S)
{
    extern __shared__ short lds[];   // 135168 B: A0|A1|B0|B1 (128K) + scratch 4K

    const int t    = threadIdx.x;    // 0..511
    const int lane = t & 63;
    const int wave = t >> 6;         // 0..7
    const int wr   = wave >> 2;      // 0..1
    const int wc   = wave & 3;       // 0..3
    const int lm   = lane & 15;
    const int lk   = lane >> 4;

    // persistent mapping: 256 blocks, 1/CU. tileM fixed per block; tileN
    // walks 4 segments. Per-XCD concurrent: 4 tileM x 8 tileN.
    const int xcd   = blockIdx.x & 7;
    const int cu    = blockIdx.x >> 3;           // 0..31
    const int tileM = xcd * 4 + (cu & 3);        // 0..31, fixed
    const int nBase = cu >> 2;                   // 0..7

    const short* Ag = Abf + (size_t)tileM * 256 * DIM;

    char* const A0 = (char*)lds;
    char* const A1 = (char*)lds + 32768;
    char* const B0 = (char*)lds + 65536;
    char* const B1 = (char*)lds + 98304;

    // B base for flattened k-tile index gg (segment = gg>>4)
#define BPTR(gg) (Bbf + (size_t)((nBase + 8 * ((gg) >> 4)) & 31) * 256 * DIM)
    // half-tile stages (2 loads/thread); h = 0/1 selects 128-row half
#define SAh(buf, h, gg) stage_half(Ag + (size_t)(h) * 128 * DIM + ((gg) & 15) * 64, \
                                   lds + (buf) * 16384 + (h) * 8192, t)
#define SBh(buf, h, gg) stage_half(BPTR(gg) + (size_t)(h) * 128 * DIM + ((gg) & 15) * 64, \
                                   lds + 32768 + (buf) * 16384 + (h) * 8192, t)

    // ---- prologue: buf0 <- g0 (4 half-tiles), then 3 half-tiles of g1.
    SAh(0, 0, 0); SBh(0, 1, 0); SAh(0, 1, 0); SBh(0, 0, 0);
    SAh(1, 0, 1); SBh(1, 1, 1); SAh(1, 1, 1);
    VM6();        // buf0 complete; {A1h0,B1h1,A1h1}(g1) in flight = steady state
    BAR();

    f32x4 acc[8][4];
#pragma unroll
    for (int m = 0; m < 8; m++)
#pragma unroll
        for (int n = 0; n < 4; n++) acc[m][n] = (f32x4){0.f, 0.f, 0.f, 0.f};

    bf16x8 aF[4][2], bF[2][2];
    constexpr float C1 = 14.4269504088896340736f;   // 10 * log2(e)

    for (int gi = 0; gi < 32; ++gi) {
        const int g = 2 * gi;            // even flattened k-tile (buf0)
        const bool s2 = (g + 2 < 64);
        const bool s3 = (g + 3 < 64);

        // ph1 : (0,0)  reads A0<0>, B0<0>; stage B1h0 <- g+1
        lda_f<0>(A0, wr, lm, lk, aF);
        ldb_f<0>(B0, wc, lm, lk, bF);
        SBh(1, 0, g + 1);
        LGKM8();
        BAR(); LGKM0();
        mma16<0, 0>(aF, bF, acc);
        BAR();
        // ph2 : (0,1)  reads B0<1>; stage A0h0 <- g+2
        ldb_f<1>(B0, wc, lm, lk, bF);
        if (s2) SAh(0, 0, g + 2);
        BAR(); LGKM0();
        mma16<0, 1>(aF, bF, acc);
        BAR();
        // ph3 : (1,1)  reads A0<1>; stage B0h1 <- g+2
        lda_f<1>(A0, wr, lm, lk, aF);
        if (s2) SBh(0, 1, g + 2);
        BAR(); LGKM0();
        mma16<1, 1>(aF, bF, acc);
        BAR();
        // ph4 : (1,0)  re-reads B0<0>; stage A0h1 <- g+2
        ldb_f<0>(B0, wc, lm, lk, bF);
        if (s2) SAh(0, 1, g + 2);
        BAR(); LGKM0();
        mma16<1, 0>(aF, bF, acc);
        if (s2) { VM6(); } else { VM0(); }   // buf1(g+1) complete before ph5
        BAR();

        // ph5 : (0,0)  reads A1<0>, B1<0>; stage B0h0 <- g+2
        lda_f<0>(A1, wr, lm, lk, aF);
        ldb_f<0>(B1, wc, lm, lk, bF);
        if (s2) SBh(0, 0, g + 2);
        LGKM8();
        BAR(); LGKM0();
        mma16<0, 0>(aF, bF, acc);
        BAR();
        // ph6 : (0,1)  reads B1<1>; stage A1h0 <- g+3
        ldb_f<1>(B1, wc, lm, lk, bF);
        if (s3) SAh(1, 0, g + 3);
        BAR(); LGKM0();
        mma16<0, 1>(aF, bF, acc);
        BAR();
        // ph7 : (1,1)  reads A1<1>; stage B1h1 <- g+3
        lda_f<1>(A1, wr, lm, lk, aF);
        if (s3) SBh(1, 1, g + 3);
        BAR(); LGKM0();
        mma16<1, 1>(aF, bF, acc);
        BAR();
        // ph8 : (1,0)  re-reads B1<0>; stage A1h1 <- g+3
        ldb_f<0>(B1, wc, lm, lk, bF);
        if (s3) SAh(1, 1, g + 3);
        BAR(); LGKM0();
        mma16<1, 0>(aF, bF, acc);
        if (s3) { VM6(); }                   // buf0(g+2) complete before next ph1
        BAR();

        // ---- segment epilogue (last local k-tile pair: g&15 == 14) ----
        if ((g & 15) == 14) {
            float* rowpart = (float*)((char*)lds + 131072);  // dedicated 4KB
#pragma unroll
            for (int mi = 0; mi < 8; mi++) {
#pragma unroll
                for (int r = 0; r < 4; r++) {
                    float s = 0.f;
#pragma unroll
                    for (int n = 0; n < 4; n++)
                        s += exp2f(fmaf(acc[mi][n][r], C1, -C1));
#pragma unroll
                    for (int msk = 1; msk < 16; msk <<= 1) s += __shfl_xor(s, msk);
                    if (lm == 0)
                        rowpart[(wr * 128 + mi * 16 + lk * 4 + r) * 4 + wc] = s;
                }
            }
            LGKM0();    // my rowpart ds_writes complete
            BAR();      // all waves' writes visible
            if (t < 256) {
                const float v = rowpart[t * 4 + 0] + rowpart[t * 4 + 1] +
                                rowpart[t * 4 + 2] + rowpart[t * 4 + 3];
                atomicAdd(&S[tileM * 256 + t], v);
            }
            // next epilogue's rowpart writes are 16 k-tiles (many barriers)
            // away; no extra barrier needed for the dedicated scratch.
#pragma unroll
            for (int m = 0; m < 8; m++)
#pragma unroll
                for (int n = 0; n < 4; n++) acc[m][n] = (f32x4){0.f, 0.f, 0.f, 0.f};
        }
    }
#undef SAh
#undef SBh
#undef BPTR
}

// ---------------------------------------------------------------------------
// Kernel 3: loss = mean_i( 10 + log(S_i) - diag_i ).  32 blocks x 256 thr,
// one atomicAdd per block (out zeroed by normalize_kernel).
// ---------------------------------------------------------------------------
__global__ __launch_bounds__(256) void loss_kernel(
    const float* __restrict__ S, const float* __restrict__ diag,
    float* __restrict__ out)
{
    const int t   = threadIdx.x;
    const int row = blockIdx.x * 256 + t;
    float acc = 10.0f + logf(S[row]) - diag[row];
#pragma unroll
    for (int m = 1; m < 64; m <<= 1) acc += __shfl_xor(acc, m);
    __shared__ float red[4];
    if ((t & 63) == 0) red[t >> 6] = acc;
    __syncthreads();
    if (t == 0) {
        const float s = red[0] + red[1] + red[2] + red[3];
        atomicAdd(out, s * (1.0f / N_ROWS));
    }
}

// ---------------------------------------------------------------------------
extern "C" void kernel_launch(void* const* d_in, const int* in_sizes, int n_in,
                              void* d_out, int out_size, void* d_ws, size_t ws_size,
                              hipStream_t stream)
{
    const float* A = (const float*)d_in[0];   // image_emb  [8192,1024] f32
    const float* B = (const float*)d_in[1];   // sensor_emb [8192,1024] f32
    float* out = (float*)d_out;

    short* a_bf = (short*)d_ws;
    short* b_bf = a_bf + (size_t)N_ROWS * DIM;
    float* S    = (float*)(b_bf + (size_t)N_ROWS * DIM);
    float* diag = S + N_ROWS;

    normalize_kernel<<<N_ROWS, 256, 0, stream>>>(A, B, a_bf, b_bf, diag, S, out);
    gemm_lse_kernel<<<256, 512, 135168, stream>>>(a_bf, b_bf, S);
    loss_kernel<<<32, 256, 0, stream>>>(S, diag, out);
}

// Round 9
// 181.502 us; speedup vs baseline: 1.3063x; 1.3063x over previous
//
#include <hip/hip_runtime.h>
#include <hip/hip_bf16.h>
#include <cstdint>

#define N_ROWS 8192
#define DIM    1024   // elements per row; == bytes per row in i8

typedef __attribute__((ext_vector_type(4))) int i32x4;

// ---------------------------------------------------------------------------
// Kernel 1: per-row L2 normalize (fp32 -> int8 global-scale-127 quant),
// fp32 diagonal logit, zero S and out.  Proven block-per-row structure.
// ---------------------------------------------------------------------------
__global__ __launch_bounds__(256) void normalize_kernel(
    const float* __restrict__ A, const float* __restrict__ B,
    char* __restrict__ Aq, char* __restrict__ Bq,
    float* __restrict__ diag, float* __restrict__ S,
    float* __restrict__ out)
{
    const int row  = blockIdx.x;
    const int t    = threadIdx.x;
    const int lane = t & 63;
    const int wave = t >> 6;

    const float4 a = reinterpret_cast<const float4*>(A)[row * (DIM / 4) + t];
    const float4 b = reinterpret_cast<const float4*>(B)[row * (DIM / 4) + t];

    float ssA = a.x * a.x + a.y * a.y + a.z * a.z + a.w * a.w;
    float ssB = b.x * b.x + b.y * b.y + b.z * b.z + b.w * b.w;
#pragma unroll
    for (int m = 1; m < 64; m <<= 1) {
        ssA += __shfl_xor(ssA, m);
        ssB += __shfl_xor(ssB, m);
    }
    __shared__ float redA[4], redB[4];
    if (lane == 0) { redA[wave] = ssA; redB[wave] = ssB; }
    __syncthreads();
    ssA = redA[0] + redA[1] + redA[2] + redA[3];
    ssB = redB[0] + redB[1] + redB[2] + redB[3];

    const float ia = 1.0f / fmaxf(sqrtf(ssA), 1e-8f);
    const float ib = 1.0f / fmaxf(sqrtf(ssB), 1e-8f);

    const float anx = a.x * ia, any = a.y * ia, anz = a.z * ia, anw = a.w * ia;
    const float bnx = b.x * ib, bny = b.y * ib, bnz = b.z * ib, bnw = b.w * ib;

    // quantize: |elem| <= 1 exactly (unit row) -> round(127*x) in [-127,127]
    const int qa = ( (__float2int_rn(anx * 127.f) & 255)        ) |
                   ( (__float2int_rn(any * 127.f) & 255) <<  8 ) |
                   ( (__float2int_rn(anz * 127.f) & 255) << 16 ) |
                   ( (__float2int_rn(anw * 127.f)      ) << 24 );
    const int qb = ( (__float2int_rn(bnx * 127.f) & 255)        ) |
                   ( (__float2int_rn(bny * 127.f) & 255) <<  8 ) |
                   ( (__float2int_rn(bnz * 127.f) & 255) << 16 ) |
                   ( (__float2int_rn(bnw * 127.f)      ) << 24 );
    reinterpret_cast<int*>(Aq)[row * (DIM / 4) + t] = qa;
    reinterpret_cast<int*>(Bq)[row * (DIM / 4) + t] = qb;

    // exact fp32 diagonal logit
    float d = anx * bnx + any * bny + anz * bnz + anw * bnw;
#pragma unroll
    for (int m = 1; m < 64; m <<= 1) d += __shfl_xor(d, m);
    __shared__ float redD[4];
    if (lane == 0) redD[wave] = d;
    __syncthreads();
    if (t == 0) {
        diag[row] = (redD[0] + redD[1] + redD[2] + redD[3]) * 10.0f;  // /T
        S[row] = 0.0f;           // ws is poisoned 0xAA each launch
        if (row == 0) out[0] = 0.0f;
    }
}

// ---------------------------------------------------------------------------
// Kernel 2: PERSISTENT 256x256x(BK=128) 8-phase INT8 GEMM (A·B^T) +
// exp(logit-10) row-sum epilogue per segment.
//   Mechanical port of the round-5 measured-best bf16 schedule to i8:
//   same 128-byte LDS rows, same byte^((row&7)<<4) swizzle (both sides),
//   same 12/4/8/4 ds_read pattern, same full-tile stages at ph1/ph4/ph5/ph8
//   with VM4 ledger, same 16-MFMA phases (ks = two K=64 halves of BK=128).
//   mfma_i32_16x16x64_i8: lane k-map (lane>>4)*16+j (family pattern),
//   C/D layout dtype-independent (m121-128) -> epilogue indexing unchanged.
//   256 blocks (1/CU): tileM fixed, 4 segments x 8 k-tiles = 32 flattened.
//   LDS: A0|A1|B0|B1 [256][128] i8 = 4x32KB + 4KB scratch = 135168 B.
// ---------------------------------------------------------------------------
#define BAR()   __builtin_amdgcn_s_barrier()
#define LGKM0() asm volatile("s_waitcnt lgkmcnt(0)" ::: "memory")
#define LGKM8() asm volatile("s_waitcnt lgkmcnt(8)" ::: "memory")
#define VM4()   asm volatile("s_waitcnt vmcnt(4)" ::: "memory")
#define VM0()   asm volatile("s_waitcnt vmcnt(0)" ::: "memory")

// stage one full 256x128 i8 tile: 512 thr x 4 x 16B; linear LDS dest,
// inverse-swizzled global source (XOR row-constant per 16B chunk; each
// global row = one permuted contiguous 128B segment -> fully coalesced).
__device__ __forceinline__ void stage_tile(const char* __restrict__ gsrc,
                                           char* ldst, int t)
{
#pragma unroll
    for (int i = 0; i < 4; i++) {
        const int d    = (i * 512 + t) * 16;                 // 0..32767
        const int row  = d >> 7;                             // 0..255
        const int colb = (d & 127) ^ ((row & 7) << 4);       // swz bits4-6
        __builtin_amdgcn_global_load_lds(
            (const __attribute__((address_space(1))) void*)(gsrc + (size_t)row * DIM + colb),
            (__attribute__((address_space(3))) void*)(ldst + d), 16, 0, 0);
    }
}

template<int MH>
__device__ __forceinline__ void lda_f(const char* base, int wr, int lm, int lk,
                                      i32x4 (&aF)[4][2])
{
#pragma unroll
    for (int m = 0; m < 4; m++)
#pragma unroll
        for (int ks = 0; ks < 2; ks++) {
            const int row = wr * 128 + MH * 64 + m * 16 + lm;
            const int b   = (row * 128 + ks * 64 + lk * 16) ^ ((row & 7) << 4);
            aF[m][ks] = *reinterpret_cast<const i32x4*>(base + b);
        }
}

template<int NH>
__device__ __forceinline__ void ldb_f(const char* base, int wc, int lm, int lk,
                                      i32x4 (&bF)[2][2])
{
#pragma unroll
    for (int n = 0; n < 2; n++)
#pragma unroll
        for (int ks = 0; ks < 2; ks++) {
            const int row = wc * 64 + NH * 32 + n * 16 + lm;
            const int b   = (row * 128 + ks * 64 + lk * 16) ^ ((row & 7) << 4);
            bF[n][ks] = *reinterpret_cast<const i32x4*>(base + b);
        }
}

template<int MH, int NP>
__device__ __forceinline__ void mma16(const i32x4 (&aF)[4][2],
                                      const i32x4 (&bF)[2][2],
                                      i32x4 (&acc)[8][4])
{
    __builtin_amdgcn_s_setprio(1);
#pragma unroll
    for (int m = 0; m < 4; m++)
#pragma unroll
        for (int n = 0; n < 2; n++)
#pragma unroll
            for (int ks = 0; ks < 2; ks++)
                acc[MH * 4 + m][NP * 2 + n] = __builtin_amdgcn_mfma_i32_16x16x64_i8(
                    aF[m][ks], bF[n][ks], acc[MH * 4 + m][NP * 2 + n], 0, 0, 0);
    __builtin_amdgcn_s_setprio(0);
}

__global__ __launch_bounds__(512, 2) void gemm_lse_kernel(
    const char* __restrict__ Aq, const char* __restrict__ Bq,
    float* __restrict__ S)
{
    extern __shared__ char lds[];    // 135168 B

    const int t    = threadIdx.x;    // 0..511
    const int lane = t & 63;
    const int wave = t >> 6;         // 0..7
    const int wr   = wave >> 2;      // 0..1
    const int wc   = wave & 3;       // 0..3
    const int lm   = lane & 15;
    const int lk   = lane >> 4;

    // persistent mapping: 256 blocks, 1/CU; tileM fixed, 4 tileN segments.
    const int xcd   = blockIdx.x & 7;
    const int cu    = blockIdx.x >> 3;           // 0..31
    const int tileM = xcd * 4 + (cu & 3);        // 0..31, fixed
    const int nBase = cu >> 2;                   // 0..7

    const char* Ag = Aq + (size_t)tileM * 256 * DIM;

    char* const A0 = lds;
    char* const A1 = lds + 32768;
    char* const B0 = lds + 65536;
    char* const B1 = lds + 98304;

    // B base for flattened k-tile gg (0..31): segment = gg>>3
#define BPTR(gg) (Bq + (size_t)((nBase + 8 * ((gg) >> 3)) & 31) * 256 * DIM)
#define SA(buf, gg) stage_tile(Ag + ((gg) & 7) * 128,        lds + (buf) * 32768,         t)
#define SB(buf, gg) stage_tile(BPTR(gg) + ((gg) & 7) * 128,  lds + 65536 + (buf) * 32768, t)

    // ---- prologue: buf0 <- g0 (8 loads), A1 <- g1 (4). VM4 -> buf0 done.
    SA(0, 0); SB(0, 0);
    SA(1, 1);
    VM4();
    BAR();

    i32x4 acc[8][4];
#pragma unroll
    for (int m = 0; m < 8; m++)
#pragma unroll
        for (int n = 0; n < 4; n++) acc[m][n] = (i32x4){0, 0, 0, 0};

    i32x4 aF[4][2], bF[2][2];
    constexpr float C1 = 14.4269504088896340736f;    // 10 * log2(e)
    constexpr float SC = C1 / 16129.0f;              // /(127^2) quant scale

    for (int gi = 0; gi < 16; ++gi) {
        const int g = 2 * gi;            // even flattened k-tile (buf0)
        const bool s2 = (g + 2 < 32);
        const bool s3 = (g + 3 < 32);

        // ph1 : (0,0)  reads A0<0>, B0<0>; stage B1 <- g+1
        lda_f<0>(A0, wr, lm, lk, aF);
        ldb_f<0>(B0, wc, lm, lk, bF);
        SB(1, g + 1);
        LGKM8();
        BAR(); LGKM0();
        mma16<0, 0>(aF, bF, acc);
        BAR();
        // ph2 : (0,1)  reads B0<1>
        ldb_f<1>(B0, wc, lm, lk, bF);
        BAR(); LGKM0();
        mma16<0, 1>(aF, bF, acc);
        BAR();
        // ph3 : (1,1)  reads A0<1>  (A0 free after)
        lda_f<1>(A0, wr, lm, lk, aF);
        BAR(); LGKM0();
        mma16<1, 1>(aF, bF, acc);
        BAR();
        // ph4 : (1,0)  re-reads B0<0> (B0 free after); stage A0 <- g+2
        ldb_f<0>(B0, wc, lm, lk, bF);
        if (s2) SA(0, g + 2);
        BAR(); LGKM0();
        mma16<1, 0>(aF, bF, acc);
        if (s2) { VM4(); } else { VM0(); }   // buf1(g+1) complete before ph5
        BAR();

        // ph5 : (0,0)  reads A1<0>, B1<0>; stage B0 <- g+2
        lda_f<0>(A1, wr, lm, lk, aF);
        ldb_f<0>(B1, wc, lm, lk, bF);
        if (s2) SB(0, g + 2);
        LGKM8();
        BAR(); LGKM0();
        mma16<0, 0>(aF, bF, acc);
        BAR();
        // ph6 : (0,1)  reads B1<1>
        ldb_f<1>(B1, wc, lm, lk, bF);
        BAR(); LGKM0();
        mma16<0, 1>(aF, bF, acc);
        BAR();
        // ph7 : (1,1)  reads A1<1>  (A1 free after)
        lda_f<1>(A1, wr, lm, lk, aF);
        BAR(); LGKM0();
        mma16<1, 1>(aF, bF, acc);
        BAR();
        // ph8 : (1,0)  re-reads B1<0> (B1 free after); stage A1 <- g+3
        ldb_f<0>(B1, wc, lm, lk, bF);
        if (s3) SA(1, g + 3);
        BAR(); LGKM0();
        mma16<1, 0>(aF, bF, acc);
        if (s3) { VM4(); }                   // buf0(g+2) complete before next ph1
        BAR();

        // ---- segment epilogue (last k-tile pair of segment: g&7 == 6) ----
        if ((g & 7) == 6) {
            float* rowpart = (float*)(lds + 131072);   // dedicated 4KB scratch
#pragma unroll
            for (int mi = 0; mi < 8; mi++) {
#pragma unroll
                for (int r = 0; r < 4; r++) {
                    float s = 0.f;
#pragma unroll
                    for (int n = 0; n < 4; n++)
                        s += exp2f(fmaf((float)acc[mi][n][r], SC, -C1));
#pragma unroll
                    for (int msk = 1; msk < 16; msk <<= 1) s += __shfl_xor(s, msk);
                    if (lm == 0)
                        rowpart[(wr * 128 + mi * 16 + lk * 4 + r) * 4 + wc] = s;
                }
            }
            LGKM0();    // my rowpart ds_writes complete
            BAR();      // all waves' writes visible
            if (t < 256) {
                const float v = rowpart[t * 4 + 0] + rowpart[t * 4 + 1] +
                                rowpart[t * 4 + 2] + rowpart[t * 4 + 3];
                atomicAdd(&S[tileM * 256 + t], v);
            }
            // next epilogue's writes are a full segment (many barriers) away.
#pragma unroll
            for (int m = 0; m < 8; m++)
#pragma unroll
                for (int n = 0; n < 4; n++) acc[m][n] = (i32x4){0, 0, 0, 0};
        }
    }
#undef SA
#undef SB
#undef BPTR
}

// ---------------------------------------------------------------------------
// Kernel 3: loss = mean_i( 10 + log(S_i) - diag_i ).  32 blocks x 256 thr,
// one atomicAdd per block (out zeroed by normalize_kernel).
// ---------------------------------------------------------------------------
__global__ __launch_bounds__(256) void loss_kernel(
    const float* __restrict__ S, const float* __restrict__ diag,
    float* __restrict__ out)
{
    const int t   = threadIdx.x;
    const int row = blockIdx.x * 256 + t;
    float acc = 10.0f + logf(S[row]) - diag[row];
#pragma unroll
    for (int m = 1; m < 64; m <<= 1) acc += __shfl_xor(acc, m);
    __shared__ float red[4];
    if ((t & 63) == 0) red[t >> 6] = acc;
    __syncthreads();
    if (t == 0) {
        const float s = red[0] + red[1] + red[2] + red[3];
        atomicAdd(out, s * (1.0f / N_ROWS));
    }
}

// ---------------------------------------------------------------------------
extern "C" void kernel_launch(void* const* d_in, const int* in_sizes, int n_in,
                              void* d_out, int out_size, void* d_ws, size_t ws_size,
                              hipStream_t stream)
{
    const float* A = (const float*)d_in[0];   // image_emb  [8192,1024] f32
    const float* B = (const float*)d_in[1];   // sensor_emb [8192,1024] f32
    float* out = (float*)d_out;

    // workspace carve: i8 A (8MB) | i8 B (8MB) | S (32KB) | diag (32KB)
    char* a_q  = (char*)d_ws;
    char* b_q  = a_q + (size_t)N_ROWS * DIM;
    float* S    = (float*)(b_q + (size_t)N_ROWS * DIM);
    float* diag = S + N_ROWS;

    normalize_kernel<<<N_ROWS, 256, 0, stream>>>(A, B, a_q, b_q, diag, S, out);
    gemm_lse_kernel<<<256, 512, 135168, stream>>>(a_q, b_q, S);
    loss_kernel<<<32, 256, 0, stream>>>(S, diag, out);
}